// Round 5
// baseline (343.697 us; speedup 1.0000x reference)
//
#include <hip/hip_runtime.h>

#define N_NODES 50000
#define N_EDGES 800000
#define F_IN 256
#define H1 8
#define N_HID 256
#define N_CLASS 47
#define MAXDEG 48
#define NW16 (N_NODES/16)   // 3125 16-row tiles

typedef __attribute__((ext_vector_type(8))) __bf16 bf16x8;
typedef __attribute__((ext_vector_type(4))) float f32x4;

__device__ __forceinline__ float bf2f(unsigned short u){
    union { unsigned int i; float f; } c; c.i = ((unsigned int)u) << 16; return c.f;
}
__device__ __forceinline__ unsigned short f2b(float f){
    union { float f; unsigned int i; } c; c.f = f;
    unsigned int u = c.i;
    unsigned int r = u + 0x7FFFu + ((u >> 16) & 1u);
    return (unsigned short)(r >> 16);
}

__global__ void k_zero(int* __restrict__ p, int n){
    int i = blockIdx.x * blockDim.x + threadIdx.x;
    if (i < n) p[i] = 0;
}

// ---- pack W1/W2 (fp32) into bf16 MFMA B-fragment order ----
// B frag (16x16x32): lane holds B[k][n], n = lane&15, k = (lane>>4)*8 + j
__global__ void k_prep_pack(const float* __restrict__ W1,
                            const float* __restrict__ W2,
                            unsigned short* __restrict__ bp1,
                            unsigned short* __restrict__ bp2){
    int tid = blockIdx.x * blockDim.x + threadIdx.x;
    if (tid < 8*2*64*8) {                       // 8192: W1, 2 col-tiles
        int j = tid & 7, lane = (tid >> 3) & 63, tile = (tid >> 9) & 1, kc = tid >> 10;
        int k = kc*32 + (lane >> 4)*8 + j;
        int n = tile*16 + (lane & 15);
        bp1[tid] = f2b(W1[k*32 + n]);
    }
    int t2 = tid - 8192;
    if (t2 >= 0 && t2 < 8*3*64*8) {             // 12288: W2, 3 col-tiles (47 -> pad 48)
        int j = t2 & 7, lane = (t2 >> 3) & 63;
        int tile = (t2 >> 9) % 3, kc = t2 / 1536;
        int k = kc*32 + (lane >> 4)*8 + j;
        int n = tile*16 + (lane & 15);
        bp2[t2] = (n < N_CLASS) ? f2b(W2[k*N_CLASS + n]) : (unsigned short)0;
    }
}

// ---- padded-CSR build (uint16 ids): one atomic per edge ----
__global__ void k_fill(const int* __restrict__ src, const int* __restrict__ dst,
                       int* __restrict__ cnt, unsigned short* __restrict__ csrp){
    int e = blockIdx.x * blockDim.x + threadIdx.x;
    if (e < N_EDGES){
        int s = src[e];
        s = ((unsigned)s < N_NODES) ? s : 0;
        int p = atomicAdd(&cnt[s], 1);
        if (p < MAXDEG) csrp[(size_t)s*MAXDEG + p] = (unsigned short)dst[e];
    }
}

// ---- GEMM1: h1[N,32] = x[N,256] @ W1[256,32]; fp32 x -> bf16 frags -> bf16 h1 ----
__global__ void k_gemm1(const float* __restrict__ x,
                        const unsigned short* __restrict__ bp1,
                        unsigned short* __restrict__ h1b){
    int wid = (blockIdx.x * blockDim.x + threadIdx.x) >> 6;
    int lane = threadIdx.x & 63;
    if (wid >= NW16) return;
    int m0 = wid * 16;
    int mrow = m0 + (lane & 15);
    int q = lane >> 4;
    f32x4 z = {0.f,0.f,0.f,0.f};
    f32x4 acc0 = z, acc1 = z;
    const float* xrow = x + (size_t)mrow * F_IN + q * 8;
    #pragma unroll
    for (int kc = 0; kc < 8; kc++){
        const f32x4* xp = (const f32x4*)(xrow + kc*32);
        f32x4 u0 = xp[0], u1 = xp[1];
        union { bf16x8 v; unsigned short s[8]; } ua;
        ua.s[0]=f2b(u0[0]); ua.s[1]=f2b(u0[1]); ua.s[2]=f2b(u0[2]); ua.s[3]=f2b(u0[3]);
        ua.s[4]=f2b(u1[0]); ua.s[5]=f2b(u1[1]); ua.s[6]=f2b(u1[2]); ua.s[7]=f2b(u1[3]);
        bf16x8 b0 = *reinterpret_cast<const bf16x8*>(bp1 + kc*1024 + lane*8);
        bf16x8 b1 = *reinterpret_cast<const bf16x8*>(bp1 + kc*1024 + 512 + lane*8);
        acc0 = __builtin_amdgcn_mfma_f32_16x16x32_bf16(ua.v, b0, acc0, 0, 0, 0);
        acc1 = __builtin_amdgcn_mfma_f32_16x16x32_bf16(ua.v, b1, acc1, 0, 0, 0);
    }
    int col = lane & 15, rbase = (lane >> 4) * 4;
    #pragma unroll
    for (int r = 0; r < 4; r++){
        int row = m0 + rbase + r;
        h1b[(size_t)row*32 + col]      = f2b(acc0[r]);
        h1b[(size_t)row*32 + 16 + col] = f2b(acc1[r]);
    }
}

// ---- el1/er1 [N,8] = h1 @ Wl1 / Wr1 (fp32 weights) ----
__global__ void k_elr1(const unsigned short* __restrict__ h1b,
                       const float* __restrict__ Wl1,
                       const float* __restrict__ Wr1,
                       float* __restrict__ el1, float* __restrict__ er1){
    int tid = blockIdx.x * blockDim.x + threadIdx.x;
    if (tid >= N_NODES * H1) return;
    int head = tid & 7, node = tid >> 3;
    float el = 0.f, er = 0.f;
    const unsigned short* hr = h1b + (size_t)node * 32;
    #pragma unroll
    for (int k = 0; k < 32; k++){
        float hv = bf2f(hr[k]);
        el += hv * Wl1[k*8 + head];
        er += hv * Wr1[k*8 + head];
    }
    el1[tid] = el; er1[tid] = er;
}

// ---- fused: layer-1 aggregation (+ELU) for 16 nodes -> LDS r-tile -> GEMM2 ----
// block = 4 waves; wave w aggregates nodes [bid*16 + w*4, +4); waves 0..2 then
// run the 16x48 MFMA from LDS into h2 (bf16).
__global__ void k_agg1g2(const unsigned short* __restrict__ h1b,
                         const float* __restrict__ el1, const float* __restrict__ er1,
                         const float* __restrict__ b1,
                         const int* __restrict__ cnt, const unsigned short* __restrict__ csrp,
                         const unsigned short* __restrict__ bp2,
                         unsigned short* __restrict__ h2b){
    __shared__ __align__(16) unsigned short lds_r[16][264];   // 528B rows, 16B-aligned
    int w = threadIdx.x >> 6, lane = threadIdx.x & 63;
    int f = lane & 31, hl = lane >> 5;
    int base = blockIdx.x * 16;
    float bv = b1[f];
    for (int i = 0; i < 4; i++){
        int node = base + w*4 + i;
        float el_i[8];
        #pragma unroll
        for (int j = 0; j < 8; j++) el_i[j] = el1[node*8 + j];
        float acc[8] = {0.f,0.f,0.f,0.f,0.f,0.f,0.f,0.f};
        float ds [8] = {0.f,0.f,0.f,0.f,0.f,0.f,0.f,0.f};
        int n = min(cnt[node], MAXDEG);
        const unsigned short* lst = csrp + (size_t)node * MAXDEG;
        for (int e = hl; e < n; e += 2){         // two wave-halves alternate edges
            int d = (int)lst[e];
            d = (d < N_NODES) ? d : 0;
            float hv = bf2f(h1b[(size_t)d*32 + f]);
            #pragma unroll
            for (int j = 0; j < 8; j++){
                float t = el_i[j] + er1[d*8 + j];
                t = (t > 0.f) ? t : 0.2f * t;
                t = fminf(t, 60.f);
                float wgt = __expf(t);
                acc[j] += wgt * hv;
                ds[j]  += wgt;
            }
        }
        #pragma unroll
        for (int j = 0; j < 8; j++){             // full-wave, all lanes active
            acc[j] += __shfl_xor(acc[j], 32);
            ds[j]  += __shfl_xor(ds[j], 32);
        }
        if (hl == 0){
            int row = w*4 + i;
            #pragma unroll
            for (int j = 0; j < 8; j++){
                float o = acc[j] / fmaxf(ds[j], 1e-12f) + bv;
                o = (o > 0.f) ? o : (__expf(o) - 1.f);   // ELU
                lds_r[row][j*32 + f] = f2b(o);
            }
        }
    }
    __syncthreads();
    if (w < 3){
        int q = lane >> 4, m = lane & 15;
        f32x4 accd = {0.f,0.f,0.f,0.f};
        #pragma unroll
        for (int kc = 0; kc < 8; kc++){
            bf16x8 a = *reinterpret_cast<const bf16x8*>(&lds_r[m][kc*32 + q*8]);
            bf16x8 b = *reinterpret_cast<const bf16x8*>(bp2 + kc*1536 + w*512 + lane*8);
            accd = __builtin_amdgcn_mfma_f32_16x16x32_bf16(a, b, accd, 0, 0, 0);
        }
        int col = lane & 15, rbase = q*4;
        #pragma unroll
        for (int r = 0; r < 4; r++){
            int grow = base + rbase + r;
            h2b[(size_t)grow*48 + w*16 + col] = f2b(accd[r]);   // col 47 = 0 via padded bp2
        }
    }
}

// ---- el2/er2 [N] = h2 @ Wl2 / Wr2 (fp32 weights; wave per node) ----
__global__ void k_elr2(const unsigned short* __restrict__ h2b,
                       const float* __restrict__ Wl2,
                       const float* __restrict__ Wr2,
                       float* __restrict__ el2, float* __restrict__ er2){
    int wid = (blockIdx.x * blockDim.x + threadIdx.x) >> 6;
    if (wid >= N_NODES) return;
    int lane = threadIdx.x & 63;
    bool valid = lane < N_CLASS;
    int cl = valid ? lane : 0;
    float hv = bf2f(h2b[(size_t)wid*48 + cl]);
    float el = valid ? hv * Wl2[cl] : 0.f;
    float er = valid ? hv * Wr2[cl] : 0.f;
    #pragma unroll
    for (int m = 32; m >= 1; m >>= 1){
        el += __shfl_xor(el, m);
        er += __shfl_xor(er, m);
    }
    if (lane == 0){ el2[wid] = el; er2[wid] = er; }
}

// ---- layer-2 aggregation + bias + log_softmax: wave per node, lane = class ----
__global__ void k_agg2(const unsigned short* __restrict__ h2b,
                       const float* __restrict__ el2, const float* __restrict__ er2,
                       const float* __restrict__ b2,
                       const int* __restrict__ cnt, const unsigned short* __restrict__ csrp,
                       float* __restrict__ out){
    int wid = (blockIdx.x * blockDim.x + threadIdx.x) >> 6;
    if (wid >= N_NODES) return;
    int lane = threadIdx.x & 63;
    bool valid = lane < N_CLASS;
    int cl = valid ? lane : 0;
    float el_i = el2[wid];
    float acc = 0.f, ds = 0.f;
    int n = min(cnt[wid], MAXDEG);
    const unsigned short* lst = csrp + (size_t)wid * MAXDEG;
    for (int e = 0; e < n; e++){
        int d = (int)lst[e];
        d = (d < N_NODES) ? d : 0;
        float t = el_i + er2[d];
        t = (t > 0.f) ? t : 0.2f * t;
        t = fminf(t, 60.f);
        float wgt = __expf(t);
        float hv = bf2f(h2b[(size_t)d*48 + cl]);
        acc += wgt * hv;
        ds  += wgt;
    }
    float o = acc / fmaxf(ds, 1e-12f) + b2[cl];
    float zm = valid ? o : -1e30f;
    #pragma unroll
    for (int m = 32; m >= 1; m >>= 1) zm = fmaxf(zm, __shfl_xor(zm, m));
    float ex = valid ? __expf(fminf(o - zm, 0.f)) : 0.f;
    #pragma unroll
    for (int m = 32; m >= 1; m >>= 1) ex += __shfl_xor(ex, m);
    float res = o - zm - __logf(ex);
    if (valid) out[(size_t)wid*N_CLASS + lane] = res;   // fp32 output
}

extern "C" void kernel_launch(void* const* d_in, const int* in_sizes, int n_in,
                              void* d_out, int out_size, void* d_ws, size_t ws_size,
                              hipStream_t stream){
    const float* x   = (const float*)d_in[0];
    const int*   esrc= (const int*)d_in[1];
    const int*   edst= (const int*)d_in[2];
    const float* W1  = (const float*)d_in[3];
    const float* Wl1 = (const float*)d_in[4];
    const float* Wr1 = (const float*)d_in[5];
    const float* b1  = (const float*)d_in[6];
    const float* W2  = (const float*)d_in[7];
    const float* Wl2 = (const float*)d_in[8];
    const float* Wr2 = (const float*)d_in[9];
    const float* b2  = (const float*)d_in[10];
    float* out = (float*)d_out;

    // total carve ~16.7 MB
    char* w = (char*)d_ws;
    auto carve = [&](size_t bytes) -> char* {
        char* p = w; w += (bytes + 255) & ~(size_t)255; return p;
    };
    int*            cnt  = (int*)            carve((size_t)N_NODES * 4);
    unsigned short* csrp = (unsigned short*) carve((size_t)N_NODES * MAXDEG * 2);
    unsigned short* h1b  = (unsigned short*) carve((size_t)N_NODES * 32 * 2);
    float*          el1  = (float*)          carve((size_t)N_NODES * 8 * 4);
    float*          er1  = (float*)          carve((size_t)N_NODES * 8 * 4);
    unsigned short* h2b  = (unsigned short*) carve((size_t)N_NODES * 48 * 2);
    float*          el2  = (float*)          carve((size_t)N_NODES * 4);
    float*          er2  = (float*)          carve((size_t)N_NODES * 4);
    unsigned short* bp1  = (unsigned short*) carve(8192 * 2);
    unsigned short* bp2  = (unsigned short*) carve(12288 * 2);

    k_zero     <<<(N_NODES + 255) / 256, 256, 0, stream>>>(cnt, N_NODES);
    k_prep_pack<<<80, 256, 0, stream>>>(W1, W2, bp1, bp2);
    k_fill     <<<(N_EDGES + 255) / 256, 256, 0, stream>>>(esrc, edst, cnt, csrp);
    k_gemm1    <<<(NW16 + 3) / 4, 256, 0, stream>>>(x, bp1, h1b);
    k_elr1     <<<(N_NODES * H1 + 255) / 256, 256, 0, stream>>>(h1b, Wl1, Wr1, el1, er1);
    k_agg1g2   <<<NW16, 256, 0, stream>>>(h1b, el1, er1, b1, cnt, csrp, bp2, h2b);
    k_elr2     <<<(N_NODES + 3) / 4, 256, 0, stream>>>(h2b, Wl2, Wr2, el2, er2);
    k_agg2     <<<(N_NODES + 3) / 4, 256, 0, stream>>>(h2b, el2, er2, b2, cnt, csrp, out);
}

// Round 6
// 319.901 us; speedup vs baseline: 1.0744x; 1.0744x over previous
//
#include <hip/hip_runtime.h>

#define N_NODES 50000
#define N_EDGES 800000
#define F_IN 256
#define H1 8
#define N_HID 256
#define N_CLASS 47
#define MAXDEG 48
#define NW16 (N_NODES/16)   // 3125 16-row tiles

typedef __attribute__((ext_vector_type(8))) __bf16 bf16x8;
typedef __attribute__((ext_vector_type(4))) float f32x4;

__device__ __forceinline__ float bf2f(unsigned short u){
    union { unsigned int i; float f; } c; c.i = ((unsigned int)u) << 16; return c.f;
}
__device__ __forceinline__ float bf2f_lo(unsigned int u){   // low 16 bits as bf16
    union { unsigned int i; float f; } c; c.i = u << 16; return c.f;
}
__device__ __forceinline__ float bf2f_hi(unsigned int u){   // high 16 bits as bf16
    union { unsigned int i; float f; } c; c.i = u & 0xffff0000u; return c.f;
}
__device__ __forceinline__ unsigned short f2b(float f){
    union { float f; unsigned int i; } c; c.f = f;
    unsigned int u = c.i;
    unsigned int r = u + 0x7FFFu + ((u >> 16) & 1u);
    return (unsigned short)(r >> 16);
}

// ---- fused prologue: zero cnt + pack W1/W2 (fp32) into bf16 MFMA B-frag order ----
// B frag (16x16x32): lane holds B[k][n], n = lane&15, k = (lane>>4)*8 + j
__global__ void k_pre(const float* __restrict__ W1,
                      const float* __restrict__ W2,
                      int* __restrict__ cnt,
                      unsigned short* __restrict__ bp1,
                      unsigned short* __restrict__ bp2){
    int tid = blockIdx.x * blockDim.x + threadIdx.x;
    if (tid < N_NODES) cnt[tid] = 0;
    if (tid < 8*2*64*8) {                       // 8192: W1, 2 col-tiles
        int j = tid & 7, lane = (tid >> 3) & 63, tile = (tid >> 9) & 1, kc = tid >> 10;
        int k = kc*32 + (lane >> 4)*8 + j;
        int n = tile*16 + (lane & 15);
        bp1[tid] = f2b(W1[k*32 + n]);
    }
    int t2 = tid - 8192;
    if (t2 >= 0 && t2 < 8*3*64*8) {             // 12288: W2, 3 col-tiles (47 -> pad 48)
        int j = t2 & 7, lane = (t2 >> 3) & 63;
        int tile = (t2 >> 9) % 3, kc = t2 / 1536;
        int k = kc*32 + (lane >> 4)*8 + j;
        int n = tile*16 + (lane & 15);
        bp2[t2] = (n < N_CLASS) ? f2b(W2[k*N_CLASS + n]) : (unsigned short)0;
    }
}

// ---- padded-CSR build (uint16 ids): one atomic per edge ----
__global__ void k_fill(const int* __restrict__ src, const int* __restrict__ dst,
                       int* __restrict__ cnt, unsigned short* __restrict__ csrp){
    int e = blockIdx.x * blockDim.x + threadIdx.x;
    if (e < N_EDGES){
        int s = src[e];
        s = ((unsigned)s < N_NODES) ? s : 0;
        int p = atomicAdd(&cnt[s], 1);
        if (p < MAXDEG) csrp[(size_t)s*MAXDEG + p] = (unsigned short)dst[e];
    }
}

// ---- GEMM1: h1[N,32] = x[N,256] @ W1[256,32]; fp32 x -> bf16 frags -> bf16 h1 ----
__global__ void k_gemm1(const float* __restrict__ x,
                        const unsigned short* __restrict__ bp1,
                        unsigned short* __restrict__ h1b){
    int wid = (blockIdx.x * blockDim.x + threadIdx.x) >> 6;
    int lane = threadIdx.x & 63;
    if (wid >= NW16) return;
    int m0 = wid * 16;
    int mrow = m0 + (lane & 15);
    int q = lane >> 4;
    f32x4 z = {0.f,0.f,0.f,0.f};
    f32x4 acc0 = z, acc1 = z;
    const float* xrow = x + (size_t)mrow * F_IN + q * 8;
    #pragma unroll
    for (int kc = 0; kc < 8; kc++){
        const f32x4* xp = (const f32x4*)(xrow + kc*32);
        f32x4 u0 = xp[0], u1 = xp[1];
        union { bf16x8 v; unsigned short s[8]; } ua;
        ua.s[0]=f2b(u0[0]); ua.s[1]=f2b(u0[1]); ua.s[2]=f2b(u0[2]); ua.s[3]=f2b(u0[3]);
        ua.s[4]=f2b(u1[0]); ua.s[5]=f2b(u1[1]); ua.s[6]=f2b(u1[2]); ua.s[7]=f2b(u1[3]);
        bf16x8 b0 = *reinterpret_cast<const bf16x8*>(bp1 + kc*1024 + lane*8);
        bf16x8 b1 = *reinterpret_cast<const bf16x8*>(bp1 + kc*1024 + 512 + lane*8);
        acc0 = __builtin_amdgcn_mfma_f32_16x16x32_bf16(ua.v, b0, acc0, 0, 0, 0);
        acc1 = __builtin_amdgcn_mfma_f32_16x16x32_bf16(ua.v, b1, acc1, 0, 0, 0);
    }
    int col = lane & 15, rbase = (lane >> 4) * 4;
    #pragma unroll
    for (int r = 0; r < 4; r++){
        int row = m0 + rbase + r;
        h1b[(size_t)row*32 + col]      = f2b(acc0[r]);
        h1b[(size_t)row*32 + 16 + col] = f2b(acc1[r]);
    }
}

// ---- el1/er1 [N,8] = h1 @ Wl1 / Wr1 (fp32 weights) ----
__global__ void k_elr1(const unsigned short* __restrict__ h1b,
                       const float* __restrict__ Wl1,
                       const float* __restrict__ Wr1,
                       float* __restrict__ el1, float* __restrict__ er1){
    int tid = blockIdx.x * blockDim.x + threadIdx.x;
    if (tid >= N_NODES * H1) return;
    int head = tid & 7, node = tid >> 3;
    float el = 0.f, er = 0.f;
    const unsigned short* hr = h1b + (size_t)node * 32;
    #pragma unroll
    for (int k = 0; k < 32; k++){
        float hv = bf2f(hr[k]);
        el += hv * Wl1[k*8 + head];
        er += hv * Wr1[k*8 + head];
    }
    el1[tid] = el; er1[tid] = er;
}

// ---- fused: layer-1 aggregation (+ELU) for 16 nodes -> LDS r-tile -> GEMM2 ----
// Relayout: lane = (head = lane>>3, featquad = lane&7); each lane owns 4 feats
// of 1 head -> 1 exp + 1 er1 gather + 1 8B h1 load + 4 fma per edge, NO
// cross-lane reduction (ds replicated within head-group; each (h,f) unique).
__global__ __launch_bounds__(256, 8)
void k_agg1g2(const unsigned short* __restrict__ h1b,
              const float* __restrict__ el1, const float* __restrict__ er1,
              const float* __restrict__ b1,
              const int* __restrict__ cnt, const unsigned short* __restrict__ csrp,
              const unsigned short* __restrict__ bp2,
              unsigned short* __restrict__ h2b){
    __shared__ __align__(16) unsigned short lds_r[16][264];   // 528B rows, 16B-aligned
    int w = threadIdx.x >> 6, lane = threadIdx.x & 63;
    int h = lane >> 3;          // head 0..7
    int fq = lane & 7;          // feature quad: features fq*4 .. fq*4+3
    int base = blockIdx.x * 16;
    int fb = fq * 4;
    float bv0 = b1[fb], bv1 = b1[fb+1], bv2 = b1[fb+2], bv3 = b1[fb+3];
    for (int i = 0; i < 4; i++){
        int node = base + w*4 + i;
        float el_h = el1[node*8 + h];
        float a0=0.f, a1=0.f, a2=0.f, a3=0.f, ds=0.f;
        int n = min(cnt[node], MAXDEG);
        const unsigned short* lst = csrp + (size_t)node * MAXDEG;
        for (int e = 0; e < n; e++){
            int d = (int)lst[e];
            uint2 hp = *(const uint2*)(h1b + (size_t)d*32 + fb);   // 4 bf16 feats
            float erv = er1[d*8 + h];
            float t = el_h + erv;
            t = (t > 0.f) ? t : 0.2f * t;
            float wv = __expf(fminf(t, 60.f));
            ds += wv;
            a0 += wv * bf2f_lo(hp.x);
            a1 += wv * bf2f_hi(hp.x);
            a2 += wv * bf2f_lo(hp.y);
            a3 += wv * bf2f_hi(hp.y);
        }
        float inv = 1.f / fmaxf(ds, 1e-12f);
        float o0 = a0*inv + bv0, o1 = a1*inv + bv1, o2 = a2*inv + bv2, o3 = a3*inv + bv3;
        o0 = (o0 > 0.f) ? o0 : (__expf(o0) - 1.f);   // ELU
        o1 = (o1 > 0.f) ? o1 : (__expf(o1) - 1.f);
        o2 = (o2 > 0.f) ? o2 : (__expf(o2) - 1.f);
        o3 = (o3 > 0.f) ? o3 : (__expf(o3) - 1.f);
        unsigned int lo = (unsigned int)f2b(o0) | ((unsigned int)f2b(o1) << 16);
        unsigned int hi = (unsigned int)f2b(o2) | ((unsigned int)f2b(o3) << 16);
        int row = w*4 + i;
        *(uint2*)&lds_r[row][h*32 + fb] = make_uint2(lo, hi);   // 8B, 8B-aligned
    }
    __syncthreads();
    if (w < 3){
        int q = lane >> 4, m = lane & 15;
        f32x4 accd = {0.f,0.f,0.f,0.f};
        #pragma unroll
        for (int kc = 0; kc < 8; kc++){
            bf16x8 a = *reinterpret_cast<const bf16x8*>(&lds_r[m][kc*32 + q*8]);
            bf16x8 b = *reinterpret_cast<const bf16x8*>(bp2 + kc*1536 + w*512 + lane*8);
            accd = __builtin_amdgcn_mfma_f32_16x16x32_bf16(a, b, accd, 0, 0, 0);
        }
        int col = lane & 15, rbase = q*4;
        #pragma unroll
        for (int r = 0; r < 4; r++){
            int grow = base + rbase + r;
            h2b[(size_t)grow*48 + w*16 + col] = f2b(accd[r]);   // col 47 = 0 via padded bp2
        }
    }
}

// ---- el2/er2 [N] = h2 @ Wl2 / Wr2 (fp32 weights; wave per node) ----
__global__ void k_elr2(const unsigned short* __restrict__ h2b,
                       const float* __restrict__ Wl2,
                       const float* __restrict__ Wr2,
                       float* __restrict__ el2, float* __restrict__ er2){
    int wid = (blockIdx.x * blockDim.x + threadIdx.x) >> 6;
    if (wid >= N_NODES) return;
    int lane = threadIdx.x & 63;
    bool valid = lane < N_CLASS;
    int cl = valid ? lane : 0;
    float hv = bf2f(h2b[(size_t)wid*48 + cl]);
    float el = valid ? hv * Wl2[cl] : 0.f;
    float er = valid ? hv * Wr2[cl] : 0.f;
    #pragma unroll
    for (int m = 32; m >= 1; m >>= 1){
        el += __shfl_xor(el, m);
        er += __shfl_xor(er, m);
    }
    if (lane == 0){ el2[wid] = el; er2[wid] = er; }
}

// ---- layer-2 aggregation + bias + log_softmax: wave per node ----
// Weights computed in parallel (lane = edge slot), then broadcast via shfl in
// the class-lane aggregation loop: no exp inside the serial loop.
__global__ __launch_bounds__(256, 8)
void k_agg2(const unsigned short* __restrict__ h2b,
            const float* __restrict__ el2, const float* __restrict__ er2,
            const float* __restrict__ b2,
            const int* __restrict__ cnt, const unsigned short* __restrict__ csrp,
            float* __restrict__ out){
    int wid = (blockIdx.x * blockDim.x + threadIdx.x) >> 6;
    if (wid >= N_NODES) return;
    int lane = threadIdx.x & 63;
    int n = min(cnt[wid], MAXDEG);
    const unsigned short* lst = csrp + (size_t)wid * MAXDEG;
    float el_i = el2[wid];
    // parallel weight computation: lane -> edge slot
    int   d_l = 0;
    float w_l = 0.f;
    if (lane < n){
        d_l = (int)lst[lane];
        float t = el_i + er2[d_l];
        t = (t > 0.f) ? t : 0.2f * t;
        w_l = __expf(fminf(t, 60.f));
    }
    float ds = w_l;
    #pragma unroll
    for (int m = 32; m >= 1; m >>= 1) ds += __shfl_xor(ds, m);
    // class-lane aggregation
    bool valid = lane < N_CLASS;
    int cl = valid ? lane : 0;
    float acc = 0.f;
    for (int e = 0; e < n; e++){
        float we = __shfl(w_l, e);
        int   de = __shfl(d_l, e);
        float hv = bf2f(h2b[(size_t)de*48 + cl]);
        acc += we * hv;
    }
    float o = acc / fmaxf(ds, 1e-12f) + b2[cl];
    float zm = valid ? o : -1e30f;
    #pragma unroll
    for (int m = 32; m >= 1; m >>= 1) zm = fmaxf(zm, __shfl_xor(zm, m));
    float ex = valid ? __expf(fminf(o - zm, 0.f)) : 0.f;
    #pragma unroll
    for (int m = 32; m >= 1; m >>= 1) ex += __shfl_xor(ex, m);
    float res = o - zm - __logf(ex);
    if (valid) out[(size_t)wid*N_CLASS + lane] = res;   // fp32 output
}

extern "C" void kernel_launch(void* const* d_in, const int* in_sizes, int n_in,
                              void* d_out, int out_size, void* d_ws, size_t ws_size,
                              hipStream_t stream){
    const float* x   = (const float*)d_in[0];
    const int*   esrc= (const int*)d_in[1];
    const int*   edst= (const int*)d_in[2];
    const float* W1  = (const float*)d_in[3];
    const float* Wl1 = (const float*)d_in[4];
    const float* Wr1 = (const float*)d_in[5];
    const float* b1  = (const float*)d_in[6];
    const float* W2  = (const float*)d_in[7];
    const float* Wl2 = (const float*)d_in[8];
    const float* Wr2 = (const float*)d_in[9];
    const float* b2  = (const float*)d_in[10];
    float* out = (float*)d_out;

    // total carve ~16.7 MB
    char* w = (char*)d_ws;
    auto carve = [&](size_t bytes) -> char* {
        char* p = w; w += (bytes + 255) & ~(size_t)255; return p;
    };
    int*            cnt  = (int*)            carve((size_t)N_NODES * 4);
    unsigned short* csrp = (unsigned short*) carve((size_t)N_NODES * MAXDEG * 2);
    unsigned short* h1b  = (unsigned short*) carve((size_t)N_NODES * 32 * 2);
    float*          el1  = (float*)          carve((size_t)N_NODES * 8 * 4);
    float*          er1  = (float*)          carve((size_t)N_NODES * 8 * 4);
    unsigned short* h2b  = (unsigned short*) carve((size_t)N_NODES * 48 * 2);
    float*          el2  = (float*)          carve((size_t)N_NODES * 4);
    float*          er2  = (float*)          carve((size_t)N_NODES * 4);
    unsigned short* bp1  = (unsigned short*) carve(8192 * 2);
    unsigned short* bp2  = (unsigned short*) carve(12288 * 2);

    k_pre    <<<(N_NODES + 255) / 256, 256, 0, stream>>>(W1, W2, cnt, bp1, bp2);
    k_fill   <<<(N_EDGES + 255) / 256, 256, 0, stream>>>(esrc, edst, cnt, csrp);
    k_gemm1  <<<(NW16 + 3) / 4, 256, 0, stream>>>(x, bp1, h1b);
    k_elr1   <<<(N_NODES * H1 + 255) / 256, 256, 0, stream>>>(h1b, Wl1, Wr1, el1, er1);
    k_agg1g2 <<<NW16, 256, 0, stream>>>(h1b, el1, er1, b1, cnt, csrp, bp2, h2b);
    k_elr2   <<<(N_NODES + 3) / 4, 256, 0, stream>>>(h2b, Wl2, Wr2, el2, er2);
    k_agg2   <<<(N_NODES + 3) / 4, 256, 0, stream>>>(h2b, el2, er2, b2, cnt, csrp, out);
}

// Round 7
// 259.393 us; speedup vs baseline: 1.3250x; 1.2333x over previous
//
#include <hip/hip_runtime.h>

#define N_NODES 50000
#define N_EDGES 800000
#define F_IN 256
#define H1 8
#define N_HID 256
#define N_CLASS 47
#define MAXDEG 48
#define NW16 (N_NODES/16)   // 3125 16-row tiles

typedef __attribute__((ext_vector_type(8))) __bf16 bf16x8;
typedef __attribute__((ext_vector_type(4))) float f32x4;

__device__ __forceinline__ float bf2f(unsigned short u){
    union { unsigned int i; float f; } c; c.i = ((unsigned int)u) << 16; return c.f;
}
__device__ __forceinline__ float bf2f_lo(unsigned int u){   // low 16 bits as bf16
    union { unsigned int i; float f; } c; c.i = u << 16; return c.f;
}
__device__ __forceinline__ float bf2f_hi(unsigned int u){   // high 16 bits as bf16
    union { unsigned int i; float f; } c; c.i = u & 0xffff0000u; return c.f;
}
__device__ __forceinline__ unsigned short f2b(float f){
    union { float f; unsigned int i; } c; c.f = f;
    unsigned int u = c.i;
    unsigned int r = u + 0x7FFFu + ((u >> 16) & 1u);
    return (unsigned short)(r >> 16);
}

// ---- fused prologue: zero cnt + pack W1/W2 (fp32) into bf16 MFMA B-frag order ----
__global__ void k_pre(const float* __restrict__ W1,
                      const float* __restrict__ W2,
                      int* __restrict__ cnt,
                      unsigned short* __restrict__ bp1,
                      unsigned short* __restrict__ bp2){
    int tid = blockIdx.x * blockDim.x + threadIdx.x;
    if (tid < N_NODES) cnt[tid] = 0;
    if (tid < 8*2*64*8) {                       // 8192: W1, 2 col-tiles
        int j = tid & 7, lane = (tid >> 3) & 63, tile = (tid >> 9) & 1, kc = tid >> 10;
        int k = kc*32 + (lane >> 4)*8 + j;
        int n = tile*16 + (lane & 15);
        bp1[tid] = f2b(W1[k*32 + n]);
    }
    int t2 = tid - 8192;
    if (t2 >= 0 && t2 < 8*3*64*8) {             // 12288: W2, 3 col-tiles (47 -> pad 48)
        int j = t2 & 7, lane = (t2 >> 3) & 63;
        int tile = (t2 >> 9) % 3, kc = t2 / 1536;
        int k = kc*32 + (lane >> 4)*8 + j;
        int n = tile*16 + (lane & 15);
        bp2[t2] = (n < N_CLASS) ? f2b(W2[k*N_CLASS + n]) : (unsigned short)0;
    }
}

// ---- padded-CSR build (uint16 ids): one atomic per edge ----
__global__ void k_fill(const int* __restrict__ src, const int* __restrict__ dst,
                       int* __restrict__ cnt, unsigned short* __restrict__ csrp){
    int e = blockIdx.x * blockDim.x + threadIdx.x;
    if (e < N_EDGES){
        int s = src[e];
        s = ((unsigned)s < N_NODES) ? s : 0;
        int p = atomicAdd(&cnt[s], 1);
        if (p < MAXDEG) csrp[(size_t)s*MAXDEG + p] = (unsigned short)dst[e];
    }
}

// ---- GEMM1: h1[N,32] = x[N,256] @ W1[256,32]; fp32 x -> bf16 frags -> bf16 h1 ----
__global__ void k_gemm1(const float* __restrict__ x,
                        const unsigned short* __restrict__ bp1,
                        unsigned short* __restrict__ h1b){
    int wid = (blockIdx.x * blockDim.x + threadIdx.x) >> 6;
    int lane = threadIdx.x & 63;
    if (wid >= NW16) return;
    int m0 = wid * 16;
    int mrow = m0 + (lane & 15);
    int q = lane >> 4;
    f32x4 z = {0.f,0.f,0.f,0.f};
    f32x4 acc0 = z, acc1 = z;
    const float* xrow = x + (size_t)mrow * F_IN + q * 8;
    #pragma unroll
    for (int kc = 0; kc < 8; kc++){
        const f32x4* xp = (const f32x4*)(xrow + kc*32);
        f32x4 u0 = xp[0], u1 = xp[1];
        union { bf16x8 v; unsigned short s[8]; } ua;
        ua.s[0]=f2b(u0[0]); ua.s[1]=f2b(u0[1]); ua.s[2]=f2b(u0[2]); ua.s[3]=f2b(u0[3]);
        ua.s[4]=f2b(u1[0]); ua.s[5]=f2b(u1[1]); ua.s[6]=f2b(u1[2]); ua.s[7]=f2b(u1[3]);
        bf16x8 b0 = *reinterpret_cast<const bf16x8*>(bp1 + kc*1024 + lane*8);
        bf16x8 b1 = *reinterpret_cast<const bf16x8*>(bp1 + kc*1024 + 512 + lane*8);
        acc0 = __builtin_amdgcn_mfma_f32_16x16x32_bf16(ua.v, b0, acc0, 0, 0, 0);
        acc1 = __builtin_amdgcn_mfma_f32_16x16x32_bf16(ua.v, b1, acc1, 0, 0, 0);
    }
    int col = lane & 15, rbase = (lane >> 4) * 4;
    #pragma unroll
    for (int r = 0; r < 4; r++){
        int row = m0 + rbase + r;
        h1b[(size_t)row*32 + col]      = f2b(acc0[r]);
        h1b[(size_t)row*32 + 16 + col] = f2b(acc1[r]);
    }
}

// ---- el1/er1 [N,8] = h1 @ Wl1 / Wr1 (fp32 weights) ----
__global__ void k_elr1(const unsigned short* __restrict__ h1b,
                       const float* __restrict__ Wl1,
                       const float* __restrict__ Wr1,
                       float* __restrict__ el1, float* __restrict__ er1){
    int tid = blockIdx.x * blockDim.x + threadIdx.x;
    if (tid >= N_NODES * H1) return;
    int head = tid & 7, node = tid >> 3;
    float el = 0.f, er = 0.f;
    const unsigned short* hr = h1b + (size_t)node * 32;
    #pragma unroll
    for (int k = 0; k < 32; k++){
        float hv = bf2f(hr[k]);
        el += hv * Wl1[k*8 + head];
        er += hv * Wr1[k*8 + head];
    }
    el1[tid] = el; er1[tid] = er;
}

// ---- fused: layer-1 aggregation (+ELU) for 16 nodes -> LDS r-tile -> GEMM2 ----
// lane = (head = lane>>3, featquad = lane&7). Edge ids prefetched wave-wide
// into registers (lane = edge slot), edge loop unrolled x4 with mask-by-zero:
// 8 independent gathers in flight per group (latency-bound fix, R6->R7).
__global__ __launch_bounds__(256, 8)
void k_agg1g2(const unsigned short* __restrict__ h1b,
              const float* __restrict__ el1, const float* __restrict__ er1,
              const float* __restrict__ b1,
              const int* __restrict__ cnt, const unsigned short* __restrict__ csrp,
              const unsigned short* __restrict__ bp2,
              unsigned short* __restrict__ h2b){
    __shared__ __align__(16) unsigned short lds_r[16][264];
    int w = threadIdx.x >> 6, lane = threadIdx.x & 63;
    int h = lane >> 3;          // head 0..7
    int fq = lane & 7;          // feature quad
    int base = blockIdx.x * 16;
    int fb = fq * 4;
    float bv0 = b1[fb], bv1 = b1[fb+1], bv2 = b1[fb+2], bv3 = b1[fb+3];
    for (int i = 0; i < 4; i++){
        int node = base + w*4 + i;
        int n = min(cnt[node], MAXDEG);
        const unsigned short* lst = csrp + (size_t)node * MAXDEG;
        // wave-wide id prefetch: lane -> edge slot; invalid slots hold 0
        int d_l = 0;
        if (lane < n){
            int dd = (int)lst[lane];
            d_l = (dd < N_NODES) ? dd : 0;
        }
        float el_h = el1[node*8 + h];
        float a0=0.f, a1=0.f, a2=0.f, a3=0.f, ds=0.f;
        for (int e = 0; e < n; e += 4){
            int d0 = __shfl(d_l, e);
            int d1 = __shfl(d_l, e+1);     // lanes >= n give d=0 (safe, masked)
            int d2 = __shfl(d_l, e+2);
            int d3 = __shfl(d_l, e+3);
            uint2 hp0 = *(const uint2*)(h1b + (size_t)d0*32 + fb);
            uint2 hp1 = *(const uint2*)(h1b + (size_t)d1*32 + fb);
            uint2 hp2 = *(const uint2*)(h1b + (size_t)d2*32 + fb);
            uint2 hp3 = *(const uint2*)(h1b + (size_t)d3*32 + fb);
            float er0 = er1[d0*8 + h];
            float er1v = er1[d1*8 + h];
            float er2v = er1[d2*8 + h];
            float er3v = er1[d3*8 + h];
            float t0 = el_h + er0;  t0 = (t0 > 0.f) ? t0 : 0.2f*t0;
            float t1 = el_h + er1v; t1 = (t1 > 0.f) ? t1 : 0.2f*t1;
            float t2 = el_h + er2v; t2 = (t2 > 0.f) ? t2 : 0.2f*t2;
            float t3 = el_h + er3v; t3 = (t3 > 0.f) ? t3 : 0.2f*t3;
            float w0 = __expf(fminf(t0, 60.f));
            float w1 = __expf(fminf(t1, 60.f));
            float w2 = __expf(fminf(t2, 60.f));
            float w3 = __expf(fminf(t3, 60.f));
            w1 = (e+1 < n) ? w1 : 0.f;     // mask tail by zero weight
            w2 = (e+2 < n) ? w2 : 0.f;
            w3 = (e+3 < n) ? w3 : 0.f;
            ds += (w0 + w1) + (w2 + w3);
            a0 += w0*bf2f_lo(hp0.x) + w1*bf2f_lo(hp1.x) + w2*bf2f_lo(hp2.x) + w3*bf2f_lo(hp3.x);
            a1 += w0*bf2f_hi(hp0.x) + w1*bf2f_hi(hp1.x) + w2*bf2f_hi(hp2.x) + w3*bf2f_hi(hp3.x);
            a2 += w0*bf2f_lo(hp0.y) + w1*bf2f_lo(hp1.y) + w2*bf2f_lo(hp2.y) + w3*bf2f_lo(hp3.y);
            a3 += w0*bf2f_hi(hp0.y) + w1*bf2f_hi(hp1.y) + w2*bf2f_hi(hp2.y) + w3*bf2f_hi(hp3.y);
        }
        float inv = 1.f / fmaxf(ds, 1e-12f);
        float o0 = a0*inv + bv0, o1 = a1*inv + bv1, o2 = a2*inv + bv2, o3 = a3*inv + bv3;
        o0 = (o0 > 0.f) ? o0 : (__expf(o0) - 1.f);   // ELU
        o1 = (o1 > 0.f) ? o1 : (__expf(o1) - 1.f);
        o2 = (o2 > 0.f) ? o2 : (__expf(o2) - 1.f);
        o3 = (o3 > 0.f) ? o3 : (__expf(o3) - 1.f);
        unsigned int lo = (unsigned int)f2b(o0) | ((unsigned int)f2b(o1) << 16);
        unsigned int hi = (unsigned int)f2b(o2) | ((unsigned int)f2b(o3) << 16);
        int row = w*4 + i;
        *(uint2*)&lds_r[row][h*32 + fb] = make_uint2(lo, hi);
    }
    __syncthreads();
    if (w < 3){
        int q = lane >> 4, m = lane & 15;
        f32x4 accd = {0.f,0.f,0.f,0.f};
        #pragma unroll
        for (int kc = 0; kc < 8; kc++){
            bf16x8 a = *reinterpret_cast<const bf16x8*>(&lds_r[m][kc*32 + q*8]);
            bf16x8 b = *reinterpret_cast<const bf16x8*>(bp2 + kc*1536 + w*512 + lane*8);
            accd = __builtin_amdgcn_mfma_f32_16x16x32_bf16(a, b, accd, 0, 0, 0);
        }
        int col = lane & 15, rbase = q*4;
        #pragma unroll
        for (int r = 0; r < 4; r++){
            int grow = base + rbase + r;
            h2b[(size_t)grow*48 + w*16 + col] = f2b(accd[r]);
        }
    }
}

// ---- el2/er2 [N] = h2 @ Wl2 / Wr2 (fp32 weights; wave per node) ----
__global__ void k_elr2(const unsigned short* __restrict__ h2b,
                       const float* __restrict__ Wl2,
                       const float* __restrict__ Wr2,
                       float* __restrict__ el2, float* __restrict__ er2){
    int wid = (blockIdx.x * blockDim.x + threadIdx.x) >> 6;
    if (wid >= N_NODES) return;
    int lane = threadIdx.x & 63;
    bool valid = lane < N_CLASS;
    int cl = valid ? lane : 0;
    float hv = bf2f(h2b[(size_t)wid*48 + cl]);
    float el = valid ? hv * Wl2[cl] : 0.f;
    float er = valid ? hv * Wr2[cl] : 0.f;
    #pragma unroll
    for (int m = 32; m >= 1; m >>= 1){
        el += __shfl_xor(el, m);
        er += __shfl_xor(er, m);
    }
    if (lane == 0){ el2[wid] = el; er2[wid] = er; }
}

// ---- layer-2 aggregation + bias + log_softmax: wave per node ----
// Lane-parallel weights; gather loop unrolled x4 into independent accumulators
// (weights are 0 beyond n -> no masking needed).
__global__ __launch_bounds__(256, 8)
void k_agg2(const unsigned short* __restrict__ h2b,
            const float* __restrict__ el2, const float* __restrict__ er2,
            const float* __restrict__ b2,
            const int* __restrict__ cnt, const unsigned short* __restrict__ csrp,
            float* __restrict__ out){
    int wid = (blockIdx.x * blockDim.x + threadIdx.x) >> 6;
    if (wid >= N_NODES) return;
    int lane = threadIdx.x & 63;
    int n = min(cnt[wid], MAXDEG);
    const unsigned short* lst = csrp + (size_t)wid * MAXDEG;
    float el_i = el2[wid];
    int   d_l = 0;
    float w_l = 0.f;
    if (lane < n){
        int dd = (int)lst[lane];
        d_l = (dd < N_NODES) ? dd : 0;
        float t = el_i + er2[d_l];
        t = (t > 0.f) ? t : 0.2f * t;
        w_l = __expf(fminf(t, 60.f));
    }
    float ds = w_l;
    #pragma unroll
    for (int m = 32; m >= 1; m >>= 1) ds += __shfl_xor(ds, m);
    bool valid = lane < N_CLASS;
    int cl = valid ? lane : 0;
    float acc0 = 0.f, acc1 = 0.f, acc2 = 0.f, acc3 = 0.f;
    for (int e = 0; e < n; e += 4){
        float we0 = __shfl(w_l, e);   int de0 = __shfl(d_l, e);
        float we1 = __shfl(w_l, e+1); int de1 = __shfl(d_l, e+1);   // w=0 beyond n
        float we2 = __shfl(w_l, e+2); int de2 = __shfl(d_l, e+2);
        float we3 = __shfl(w_l, e+3); int de3 = __shfl(d_l, e+3);
        acc0 += we0 * bf2f(h2b[(size_t)de0*48 + cl]);
        acc1 += we1 * bf2f(h2b[(size_t)de1*48 + cl]);
        acc2 += we2 * bf2f(h2b[(size_t)de2*48 + cl]);
        acc3 += we3 * bf2f(h2b[(size_t)de3*48 + cl]);
    }
    float acc = (acc0 + acc1) + (acc2 + acc3);
    float o = acc / fmaxf(ds, 1e-12f) + b2[cl];
    float zm = valid ? o : -1e30f;
    #pragma unroll
    for (int m = 32; m >= 1; m >>= 1) zm = fmaxf(zm, __shfl_xor(zm, m));
    float ex = valid ? __expf(fminf(o - zm, 0.f)) : 0.f;
    #pragma unroll
    for (int m = 32; m >= 1; m >>= 1) ex += __shfl_xor(ex, m);
    float res = o - zm - __logf(ex);
    if (valid) out[(size_t)wid*N_CLASS + lane] = res;   // fp32 output
}

extern "C" void kernel_launch(void* const* d_in, const int* in_sizes, int n_in,
                              void* d_out, int out_size, void* d_ws, size_t ws_size,
                              hipStream_t stream){
    const float* x   = (const float*)d_in[0];
    const int*   esrc= (const int*)d_in[1];
    const int*   edst= (const int*)d_in[2];
    const float* W1  = (const float*)d_in[3];
    const float* Wl1 = (const float*)d_in[4];
    const float* Wr1 = (const float*)d_in[5];
    const float* b1  = (const float*)d_in[6];
    const float* W2  = (const float*)d_in[7];
    const float* Wl2 = (const float*)d_in[8];
    const float* Wr2 = (const float*)d_in[9];
    const float* b2  = (const float*)d_in[10];
    float* out = (float*)d_out;

    char* w = (char*)d_ws;
    auto carve = [&](size_t bytes) -> char* {
        char* p = w; w += (bytes + 255) & ~(size_t)255; return p;
    };
    int*            cnt  = (int*)            carve((size_t)N_NODES * 4);
    unsigned short* csrp = (unsigned short*) carve((size_t)N_NODES * MAXDEG * 2);
    unsigned short* h1b  = (unsigned short*) carve((size_t)N_NODES * 32 * 2);
    float*          el1  = (float*)          carve((size_t)N_NODES * 8 * 4);
    float*          er1  = (float*)          carve((size_t)N_NODES * 8 * 4);
    unsigned short* h2b  = (unsigned short*) carve((size_t)N_NODES * 48 * 2);
    float*          el2  = (float*)          carve((size_t)N_NODES * 4);
    float*          er2  = (float*)          carve((size_t)N_NODES * 4);
    unsigned short* bp1  = (unsigned short*) carve(8192 * 2);
    unsigned short* bp2  = (unsigned short*) carve(12288 * 2);

    k_pre    <<<(N_NODES + 255) / 256, 256, 0, stream>>>(W1, W2, cnt, bp1, bp2);
    k_fill   <<<(N_EDGES + 255) / 256, 256, 0, stream>>>(esrc, edst, cnt, csrp);
    k_gemm1  <<<(NW16 + 3) / 4, 256, 0, stream>>>(x, bp1, h1b);
    k_elr1   <<<(N_NODES * H1 + 255) / 256, 256, 0, stream>>>(h1b, Wl1, Wr1, el1, er1);
    k_agg1g2 <<<NW16, 256, 0, stream>>>(h1b, el1, er1, b1, cnt, csrp, bp2, h2b);
    k_elr2   <<<(N_NODES + 3) / 4, 256, 0, stream>>>(h2b, Wl2, Wr2, el2, er2);
    k_agg2   <<<(N_NODES + 3) / 4, 256, 0, stream>>>(h2b, el2, er2, b2, cnt, csrp, out);
}

// Round 8
// 247.135 us; speedup vs baseline: 1.3907x; 1.0496x over previous
//
#include <hip/hip_runtime.h>

#define N_NODES 50000
#define N_EDGES 800000
#define F_IN 256
#define H1 8
#define N_HID 256
#define N_CLASS 47
#define MAXDEG 48
#define NW16 (N_NODES/16)   // 3125 16-row tiles

typedef __attribute__((ext_vector_type(8))) __bf16 bf16x8;
typedef __attribute__((ext_vector_type(4))) float f32x4;

__device__ __forceinline__ float bf2f(unsigned short u){
    union { unsigned int i; float f; } c; c.i = ((unsigned int)u) << 16; return c.f;
}
__device__ __forceinline__ float bf2f_lo(unsigned int u){
    union { unsigned int i; float f; } c; c.i = u << 16; return c.f;
}
__device__ __forceinline__ float bf2f_hi(unsigned int u){
    union { unsigned int i; float f; } c; c.i = u & 0xffff0000u; return c.f;
}
__device__ __forceinline__ unsigned short f2b(float f){
    union { float f; unsigned int i; } c; c.f = f;
    unsigned int u = c.i;
    unsigned int r = u + 0x7FFFu + ((u >> 16) & 1u);
    return (unsigned short)(r >> 16);
}

// ---- prologue: zero cnt + pack W1/W2 B-frags + pack [Wl1|Wr1] B-frag ----
// B frag (16x16x32): lane holds B[k][n], n = lane&15, k = (lane>>4)*8 + j
__global__ void k_pre(const float* __restrict__ W1,
                      const float* __restrict__ W2,
                      const float* __restrict__ Wl1,
                      const float* __restrict__ Wr1,
                      int* __restrict__ cnt,
                      unsigned short* __restrict__ bp1,
                      unsigned short* __restrict__ bp2,
                      unsigned short* __restrict__ bp3){
    int tid = blockIdx.x * blockDim.x + threadIdx.x;
    if (tid < N_NODES) cnt[tid] = 0;
    if (tid < 8*2*64*8) {                       // 8192: W1, 2 col-tiles
        int j = tid & 7, lane = (tid >> 3) & 63, tile = (tid >> 9) & 1, kc = tid >> 10;
        int k = kc*32 + (lane >> 4)*8 + j;
        int n = tile*16 + (lane & 15);
        bp1[tid] = f2b(W1[k*32 + n]);
    }
    int t2 = tid - 8192;
    if (t2 >= 0 && t2 < 8*3*64*8) {             // 12288: W2, 3 col-tiles (pad 48)
        int j = t2 & 7, lane = (t2 >> 3) & 63;
        int tile = (t2 >> 9) % 3, kc = t2 / 1536;
        int k = kc*32 + (lane >> 4)*8 + j;
        int n = tile*16 + (lane & 15);
        bp2[t2] = (n < N_CLASS) ? f2b(W2[k*N_CLASS + n]) : (unsigned short)0;
    }
    int t3 = tid - 20480;
    if (t3 >= 0 && t3 < 512) {                  // [Wl1|Wr1]: K=32, N=16 (8 el + 8 er)
        int j = t3 & 7, lane = t3 >> 3;
        int n = lane & 15, k = (lane >> 4)*8 + j;
        bp3[t3] = (n < 8) ? f2b(Wl1[k*8 + n]) : f2b(Wr1[k*8 + (n - 8)]);
    }
}

// ---- padded-CSR build (uint16 ids): one atomic per edge ----
__global__ void k_fill(const int* __restrict__ src, const int* __restrict__ dst,
                       int* __restrict__ cnt, unsigned short* __restrict__ csrp){
    int e = blockIdx.x * blockDim.x + threadIdx.x;
    if (e < N_EDGES){
        int s = src[e];
        s = ((unsigned)s < N_NODES) ? s : 0;
        int p = atomicAdd(&cnt[s], 1);
        if (p < MAXDEG) csrp[(size_t)s*MAXDEG + p] = (unsigned short)dst[e];
    }
}

// ---- GEMM1 + fused elr1: h1 = x@W1 (MFMA); el1/er1 = h1@[Wl1|Wr1] (MFMA) ----
// h1-tile round-trips per-wave LDS (C-layout -> A-frag layout, stride 40).
__global__ __launch_bounds__(256)
void k_gemm1(const float* __restrict__ x,
             const unsigned short* __restrict__ bp1,
             const unsigned short* __restrict__ bp3,
             unsigned short* __restrict__ h1b,
             float* __restrict__ el1, float* __restrict__ er1){
    __shared__ __align__(16) unsigned short lds_h[4][16][40];
    int w = threadIdx.x >> 6;
    int wid = (blockIdx.x * blockDim.x + threadIdx.x) >> 6;
    int lane = threadIdx.x & 63;
    if (wid >= NW16) return;
    int m0 = wid * 16;
    int mrow = m0 + (lane & 15);
    int q = lane >> 4;
    f32x4 z = {0.f,0.f,0.f,0.f};
    f32x4 acc0 = z, acc1 = z;
    const float* xrow = x + (size_t)mrow * F_IN + q * 8;
    #pragma unroll
    for (int kc = 0; kc < 8; kc++){
        const f32x4* xp = (const f32x4*)(xrow + kc*32);
        f32x4 u0 = xp[0], u1 = xp[1];
        union { bf16x8 v; unsigned short s[8]; } ua;
        ua.s[0]=f2b(u0[0]); ua.s[1]=f2b(u0[1]); ua.s[2]=f2b(u0[2]); ua.s[3]=f2b(u0[3]);
        ua.s[4]=f2b(u1[0]); ua.s[5]=f2b(u1[1]); ua.s[6]=f2b(u1[2]); ua.s[7]=f2b(u1[3]);
        bf16x8 b0 = *reinterpret_cast<const bf16x8*>(bp1 + kc*1024 + lane*8);
        bf16x8 b1 = *reinterpret_cast<const bf16x8*>(bp1 + kc*1024 + 512 + lane*8);
        acc0 = __builtin_amdgcn_mfma_f32_16x16x32_bf16(ua.v, b0, acc0, 0, 0, 0);
        acc1 = __builtin_amdgcn_mfma_f32_16x16x32_bf16(ua.v, b1, acc1, 0, 0, 0);
    }
    int col = lane & 15, rbase = q * 4;
    #pragma unroll
    for (int r = 0; r < 4; r++){
        int row = m0 + rbase + r;
        unsigned short v0 = f2b(acc0[r]), v1 = f2b(acc1[r]);
        h1b[(size_t)row*32 + col]      = v0;
        h1b[(size_t)row*32 + 16 + col] = v1;
        lds_h[w][rbase + r][col]      = v0;   // wave-local transpose staging
        lds_h[w][rbase + r][16 + col] = v1;
    }
    // within-wave LDS: ds ops are wave-ordered; compiler inserts lgkmcnt wait
    bf16x8 a2 = *reinterpret_cast<const bf16x8*>(&lds_h[w][lane & 15][q*8]);
    bf16x8 b3 = *reinterpret_cast<const bf16x8*>(bp3 + lane*8);
    f32x4 e = z;
    e = __builtin_amdgcn_mfma_f32_16x16x32_bf16(a2, b3, e, 0, 0, 0);
    #pragma unroll
    for (int r = 0; r < 4; r++){
        int row = m0 + rbase + r;
        if (col < 8) el1[(size_t)row*8 + col]     = e[r];
        else         er1[(size_t)row*8 + col - 8] = e[r];
    }
}

// ---- fused: agg1 (+ELU) for 16 nodes -> LDS -> GEMM2 -> h2 + fused elr2 ----
// lane = (head = lane>>3, featquad = lane&7). All 4 nodes' edge ids / el1 /
// cnt prefetched up front; edge loop unrolled x8 (16 gathers in flight).
__global__ __launch_bounds__(256)
void k_agg1g2(const unsigned short* __restrict__ h1b,
              const float* __restrict__ el1, const float* __restrict__ er1,
              const float* __restrict__ b1,
              const float* __restrict__ Wl2, const float* __restrict__ Wr2,
              const int* __restrict__ cnt, const unsigned short* __restrict__ csrp,
              const unsigned short* __restrict__ bp2,
              unsigned short* __restrict__ h2b,
              float* __restrict__ el2, float* __restrict__ er2){
    __shared__ __align__(16) unsigned short lds_r[16][264];
    __shared__ float lds_p[2][3][16];
    int w = threadIdx.x >> 6, lane = threadIdx.x & 63;
    int h = lane >> 3, fq = lane & 7, fb = fq * 4;
    int base = blockIdx.x * 16;
    int node0 = base + w * 4;
    int4 n4 = *(const int4*)(cnt + node0);            // 16B-aligned
    int n_[4] = { min(n4.x, MAXDEG), min(n4.y, MAXDEG),
                  min(n4.z, MAXDEG), min(n4.w, MAXDEG) };
    int dl[4];                                        // prefetch edge ids, 4 nodes
    #pragma unroll
    for (int i = 0; i < 4; i++){
        const unsigned short* lst = csrp + (size_t)(node0 + i) * MAXDEG;
        int dd = (lane < MAXDEG) ? (int)lst[lane] : 0;
        dl[i] = (dd < N_NODES) ? dd : 0;
    }
    float elh[4];
    #pragma unroll
    for (int i = 0; i < 4; i++) elh[i] = el1[(node0 + i)*8 + h];
    float bv0 = b1[fb], bv1 = b1[fb+1], bv2 = b1[fb+2], bv3 = b1[fb+3];
    #pragma unroll
    for (int i = 0; i < 4; i++){
        int n = n_[i];
        float el_h = elh[i];
        float a0=0.f, a1=0.f, a2=0.f, a3=0.f, ds=0.f;
        for (int e = 0; e < n; e += 8){
            int d0 = __shfl(dl[i], e);
            int d1 = __shfl(dl[i], e+1);
            int d2 = __shfl(dl[i], e+2);
            int d3 = __shfl(dl[i], e+3);
            int d4 = __shfl(dl[i], e+4);
            int d5 = __shfl(dl[i], e+5);
            int d6 = __shfl(dl[i], e+6);
            int d7 = __shfl(dl[i], e+7);
            uint2 hp0 = *(const uint2*)(h1b + (size_t)d0*32 + fb);
            uint2 hp1 = *(const uint2*)(h1b + (size_t)d1*32 + fb);
            uint2 hp2 = *(const uint2*)(h1b + (size_t)d2*32 + fb);
            uint2 hp3 = *(const uint2*)(h1b + (size_t)d3*32 + fb);
            uint2 hp4 = *(const uint2*)(h1b + (size_t)d4*32 + fb);
            uint2 hp5 = *(const uint2*)(h1b + (size_t)d5*32 + fb);
            uint2 hp6 = *(const uint2*)(h1b + (size_t)d6*32 + fb);
            uint2 hp7 = *(const uint2*)(h1b + (size_t)d7*32 + fb);
            float e0 = er1[d0*8 + h], e1 = er1[d1*8 + h];
            float e2 = er1[d2*8 + h], e3 = er1[d3*8 + h];
            float e4 = er1[d4*8 + h], e5 = er1[d5*8 + h];
            float e6 = er1[d6*8 + h], e7 = er1[d7*8 + h];
            float t0 = el_h+e0; t0 = (t0>0.f)?t0:0.2f*t0;
            float t1 = el_h+e1; t1 = (t1>0.f)?t1:0.2f*t1;
            float t2 = el_h+e2; t2 = (t2>0.f)?t2:0.2f*t2;
            float t3 = el_h+e3; t3 = (t3>0.f)?t3:0.2f*t3;
            float t4 = el_h+e4; t4 = (t4>0.f)?t4:0.2f*t4;
            float t5 = el_h+e5; t5 = (t5>0.f)?t5:0.2f*t5;
            float t6 = el_h+e6; t6 = (t6>0.f)?t6:0.2f*t6;
            float t7 = el_h+e7; t7 = (t7>0.f)?t7:0.2f*t7;
            float w0 = __expf(fminf(t0,60.f));
            float w1 = __expf(fminf(t1,60.f)); w1 = (e+1<n)?w1:0.f;
            float w2 = __expf(fminf(t2,60.f)); w2 = (e+2<n)?w2:0.f;
            float w3 = __expf(fminf(t3,60.f)); w3 = (e+3<n)?w3:0.f;
            float w4 = __expf(fminf(t4,60.f)); w4 = (e+4<n)?w4:0.f;
            float w5 = __expf(fminf(t5,60.f)); w5 = (e+5<n)?w5:0.f;
            float w6 = __expf(fminf(t6,60.f)); w6 = (e+6<n)?w6:0.f;
            float w7 = __expf(fminf(t7,60.f)); w7 = (e+7<n)?w7:0.f;
            ds += ((w0+w1)+(w2+w3)) + ((w4+w5)+(w6+w7));
            a0 += w0*bf2f_lo(hp0.x) + w1*bf2f_lo(hp1.x) + w2*bf2f_lo(hp2.x) + w3*bf2f_lo(hp3.x)
                + w4*bf2f_lo(hp4.x) + w5*bf2f_lo(hp5.x) + w6*bf2f_lo(hp6.x) + w7*bf2f_lo(hp7.x);
            a1 += w0*bf2f_hi(hp0.x) + w1*bf2f_hi(hp1.x) + w2*bf2f_hi(hp2.x) + w3*bf2f_hi(hp3.x)
                + w4*bf2f_hi(hp4.x) + w5*bf2f_hi(hp5.x) + w6*bf2f_hi(hp6.x) + w7*bf2f_hi(hp7.x);
            a2 += w0*bf2f_lo(hp0.y) + w1*bf2f_lo(hp1.y) + w2*bf2f_lo(hp2.y) + w3*bf2f_lo(hp3.y)
                + w4*bf2f_lo(hp4.y) + w5*bf2f_lo(hp5.y) + w6*bf2f_lo(hp6.y) + w7*bf2f_lo(hp7.y);
            a3 += w0*bf2f_hi(hp0.y) + w1*bf2f_hi(hp1.y) + w2*bf2f_hi(hp2.y) + w3*bf2f_hi(hp3.y)
                + w4*bf2f_hi(hp4.y) + w5*bf2f_hi(hp5.y) + w6*bf2f_hi(hp6.y) + w7*bf2f_hi(hp7.y);
        }
        float inv = 1.f / fmaxf(ds, 1e-12f);
        float o0 = a0*inv + bv0, o1 = a1*inv + bv1, o2 = a2*inv + bv2, o3 = a3*inv + bv3;
        o0 = (o0 > 0.f) ? o0 : (__expf(o0) - 1.f);
        o1 = (o1 > 0.f) ? o1 : (__expf(o1) - 1.f);
        o2 = (o2 > 0.f) ? o2 : (__expf(o2) - 1.f);
        o3 = (o3 > 0.f) ? o3 : (__expf(o3) - 1.f);
        unsigned int lo = (unsigned int)f2b(o0) | ((unsigned int)f2b(o1) << 16);
        unsigned int hi = (unsigned int)f2b(o2) | ((unsigned int)f2b(o3) << 16);
        *(uint2*)&lds_r[w*4 + i][h*32 + fb] = make_uint2(lo, hi);
    }
    __syncthreads();
    if (w < 3){
        int q = lane >> 4, m = lane & 15;
        f32x4 accd = {0.f,0.f,0.f,0.f};
        #pragma unroll
        for (int kc = 0; kc < 8; kc++){
            bf16x8 a = *reinterpret_cast<const bf16x8*>(&lds_r[m][kc*32 + q*8]);
            bf16x8 b = *reinterpret_cast<const bf16x8*>(bp2 + kc*1536 + w*512 + lane*8);
            accd = __builtin_amdgcn_mfma_f32_16x16x32_bf16(a, b, accd, 0, 0, 0);
        }
        int col = lane & 15, rbase = q * 4;
        int cls = w*16 + col;
        float wl2v = (cls < N_CLASS) ? Wl2[cls] : 0.f;
        float wr2v = (cls < N_CLASS) ? Wr2[cls] : 0.f;
        float pe[4], pr[4];
        #pragma unroll
        for (int r = 0; r < 4; r++){
            int grow = base + rbase + r;
            h2b[(size_t)grow*48 + w*16 + col] = f2b(accd[r]);
            pe[r] = accd[r] * wl2v;
            pr[r] = accd[r] * wr2v;
        }
        #pragma unroll
        for (int msk = 1; msk <= 8; msk <<= 1){
            #pragma unroll
            for (int r = 0; r < 4; r++){
                pe[r] += __shfl_xor(pe[r], msk);
                pr[r] += __shfl_xor(pr[r], msk);
            }
        }
        if (col == 0){
            #pragma unroll
            for (int r = 0; r < 4; r++){
                lds_p[0][w][rbase + r] = pe[r];
                lds_p[1][w][rbase + r] = pr[r];
            }
        }
    }
    __syncthreads();
    if (w == 3 && lane < 16){
        float ev = lds_p[0][0][lane] + lds_p[0][1][lane] + lds_p[0][2][lane];
        float rv = lds_p[1][0][lane] + lds_p[1][1][lane] + lds_p[1][2][lane];
        el2[base + lane] = ev;
        er2[base + lane] = rv;
    }
}

// ---- layer-2 aggregation + bias + log_softmax: wave per node, unroll x8 ----
__global__ __launch_bounds__(256)
void k_agg2(const unsigned short* __restrict__ h2b,
            const float* __restrict__ el2, const float* __restrict__ er2,
            const float* __restrict__ b2,
            const int* __restrict__ cnt, const unsigned short* __restrict__ csrp,
            float* __restrict__ out){
    int wid = (blockIdx.x * blockDim.x + threadIdx.x) >> 6;
    if (wid >= N_NODES) return;
    int lane = threadIdx.x & 63;
    int n = min(cnt[wid], MAXDEG);
    const unsigned short* lst = csrp + (size_t)wid * MAXDEG;
    float el_i = el2[wid];
    int   d_l = 0;
    float w_l = 0.f;
    if (lane < n){
        int dd = (int)lst[lane];
        d_l = (dd < N_NODES) ? dd : 0;
        float t = el_i + er2[d_l];
        t = (t > 0.f) ? t : 0.2f * t;
        w_l = __expf(fminf(t, 60.f));
    }
    float ds = w_l;
    #pragma unroll
    for (int m = 32; m >= 1; m >>= 1) ds += __shfl_xor(ds, m);
    bool valid = lane < N_CLASS;
    int cl = valid ? lane : 0;
    float acc0=0.f, acc1=0.f, acc2=0.f, acc3=0.f;
    for (int e = 0; e < n; e += 8){
        float we0 = __shfl(w_l, e);   int de0 = __shfl(d_l, e);
        float we1 = __shfl(w_l, e+1); int de1 = __shfl(d_l, e+1);
        float we2 = __shfl(w_l, e+2); int de2 = __shfl(d_l, e+2);
        float we3 = __shfl(w_l, e+3); int de3 = __shfl(d_l, e+3);
        float we4 = __shfl(w_l, e+4); int de4 = __shfl(d_l, e+4);
        float we5 = __shfl(w_l, e+5); int de5 = __shfl(d_l, e+5);
        float we6 = __shfl(w_l, e+6); int de6 = __shfl(d_l, e+6);
        float we7 = __shfl(w_l, e+7); int de7 = __shfl(d_l, e+7);
        acc0 += we0 * bf2f(h2b[(size_t)de0*48 + cl]);
        acc1 += we1 * bf2f(h2b[(size_t)de1*48 + cl]);
        acc2 += we2 * bf2f(h2b[(size_t)de2*48 + cl]);
        acc3 += we3 * bf2f(h2b[(size_t)de3*48 + cl]);
        acc0 += we4 * bf2f(h2b[(size_t)de4*48 + cl]);
        acc1 += we5 * bf2f(h2b[(size_t)de5*48 + cl]);
        acc2 += we6 * bf2f(h2b[(size_t)de6*48 + cl]);
        acc3 += we7 * bf2f(h2b[(size_t)de7*48 + cl]);
    }
    float acc = (acc0 + acc1) + (acc2 + acc3);
    float o = acc / fmaxf(ds, 1e-12f) + b2[cl];
    float zm = valid ? o : -1e30f;
    #pragma unroll
    for (int m = 32; m >= 1; m >>= 1) zm = fmaxf(zm, __shfl_xor(zm, m));
    float ex = valid ? __expf(fminf(o - zm, 0.f)) : 0.f;
    #pragma unroll
    for (int m = 32; m >= 1; m >>= 1) ex += __shfl_xor(ex, m);
    float res = o - zm - __logf(ex);
    if (valid) out[(size_t)wid*N_CLASS + lane] = res;
}

extern "C" void kernel_launch(void* const* d_in, const int* in_sizes, int n_in,
                              void* d_out, int out_size, void* d_ws, size_t ws_size,
                              hipStream_t stream){
    const float* x   = (const float*)d_in[0];
    const int*   esrc= (const int*)d_in[1];
    const int*   edst= (const int*)d_in[2];
    const float* W1  = (const float*)d_in[3];
    const float* Wl1 = (const float*)d_in[4];
    const float* Wr1 = (const float*)d_in[5];
    const float* b1  = (const float*)d_in[6];
    const float* W2  = (const float*)d_in[7];
    const float* Wl2 = (const float*)d_in[8];
    const float* Wr2 = (const float*)d_in[9];
    const float* b2  = (const float*)d_in[10];
    float* out = (float*)d_out;

    char* w = (char*)d_ws;
    auto carve = [&](size_t bytes) -> char* {
        char* p = w; w += (bytes + 255) & ~(size_t)255; return p;
    };
    int*            cnt  = (int*)            carve((size_t)N_NODES * 4);
    unsigned short* csrp = (unsigned short*) carve((size_t)N_NODES * MAXDEG * 2);
    unsigned short* h1b  = (unsigned short*) carve((size_t)N_NODES * 32 * 2);
    float*          el1  = (float*)          carve((size_t)N_NODES * 8 * 4);
    float*          er1  = (float*)          carve((size_t)N_NODES * 8 * 4);
    unsigned short* h2b  = (unsigned short*) carve((size_t)N_NODES * 48 * 2);
    float*          el2  = (float*)          carve((size_t)N_NODES * 4);
    float*          er2  = (float*)          carve((size_t)N_NODES * 4);
    unsigned short* bp1  = (unsigned short*) carve(8192 * 2);
    unsigned short* bp2  = (unsigned short*) carve(12288 * 2);
    unsigned short* bp3  = (unsigned short*) carve(512 * 2);

    k_pre    <<<(N_NODES + 255) / 256, 256, 0, stream>>>(W1, W2, Wl1, Wr1, cnt, bp1, bp2, bp3);
    k_fill   <<<(N_EDGES + 255) / 256, 256, 0, stream>>>(esrc, edst, cnt, csrp);
    k_gemm1  <<<(NW16 + 3) / 4, 256, 0, stream>>>(x, bp1, bp3, h1b, el1, er1);
    k_agg1g2 <<<NW16, 256, 0, stream>>>(h1b, el1, er1, b1, Wl2, Wr2, cnt, csrp, bp2, h2b, el2, er2);
    k_agg2   <<<(N_NODES + 3) / 4, 256, 0, stream>>>(h2b, el2, er2, b2, cnt, csrp, out);
}